// Round 5
// baseline (380.068 us; speedup 1.0000x reference)
//
#include <hip/hip_runtime.h>

// ---- problem constants ----
static constexpr int SEQ = 20, FEAT = 5, NU1 = 10, NU2 = 7, NU3 = 4, NOUT = 4;

// MFMA fragment types
typedef short bf16x8 __attribute__((ext_vector_type(8)));
typedef float f32x4  __attribute__((ext_vector_type(4)));

// Bias B-pair: (hi=1.0, lo=0.0) -> K-slots (1,0,1,0); paired with uniform
// A-pattern (bhi,bhi,blo,blo) gives exactly bhi+blo.
static constexpr unsigned ONE_P = 0x00003F80u;

// ---- K-slot scheme ----
// Input i -> 4 K-slots: A=(Whi,Whi,Wlo,Wlo), B=(vhi,vlo,vhi,vlo); sum=(Whi+Wlo)(vhi+vlo).
// A-fragments stored COMPRESSED: per lane uint2 {W0hi|W0lo<<16, W1hi|W1lo<<16};
// expanded to the 8-slot layout with 4 v_perm right before each MFMA (keeps the
// loop-invariant fragment pool at 30 VGPRs instead of 60 AGPRs -> 5 waves/SIMD).
// Lane (n = lane&15 batch-col, q = lane>>4) supplies B inputs (8*kap+2q, 8*kap+2q+1).
// INTERLEAVED input orderings make recurrent B-frags lane-local:
//  L1: [h1_0,h1_4,h1_1,h1_5,h1_2,h1_6,h1_3,h1_7 | h1_8,h1_9,x0..x4,b1]
//  L2: [h1 pairs | h1_8,h1_9,h2_0,h2_4,h2_1,h2_5 | h2_2,h2_6,h2_3,b2]
//  L3: [h2_0,h2_4,h2_1,h2_5,h2_2,h2_6,h2_3,h3_0 | h3_1,h3_2,h3_3,b3]
//  D : [h3_0,h3_1,h3_2,h3_3,bd], A-rows REPLICATED so every lane gets all 4 outputs.
// Cross-lane: 5 bpermutes/timestep (t9, s2a/s2b, rot/rot2).
// Dense sigmoid DEFERRED: 4 sigm/t -> 1 sigm/t amortized.
// Gate activations use combined reciprocals (5 exp + 2 rcp per act):
//  c' = [c*di*dg + (eg-1)*df] / (df*di*dg),  h = (ec-1)/((1+eo)(1+ec)).

__device__ __forceinline__ unsigned short bf16_hi_rne(float x) {
    unsigned u = __float_as_uint(x);
    return (unsigned short)((u + 0x7FFF + ((u >> 16) & 1)) >> 16);
}
__device__ __forceinline__ unsigned short bf16_trunc(float x) {
    return (unsigned short)(__float_as_uint(x) >> 16);
}
__device__ __forceinline__ float bf16_to_f(unsigned short h) {
    return __uint_as_float(((unsigned)h) << 16);
}
// pack value as (hi | lo<<16): hi = RNE bf16 via v_cvt_pk, lo = trunc(h - hi)
__device__ __forceinline__ unsigned hpack(float h) {
    unsigned rp;
    asm("v_cvt_pk_bf16_f32 %0, %1, %1" : "=v"(rp) : "v"(h));
    float lo = h - __uint_as_float(rp << 16);
    return __builtin_amdgcn_perm(__float_as_uint(lo), rp, 0x07060100u);
}

__device__ __forceinline__ float sigm(float x) {
    return __builtin_amdgcn_rcpf(1.0f + __builtin_amdgcn_exp2f(x * -1.4426950408889634f));
}

// z = (i,f,g,o) for one unit (lane-local); updates c, returns packed h (hi,lo).
// Combined-reciprocal form: 5 exp + 2 rcp (was 5 exp + 5 rcp).
//  sigm(f)*c + sigm(i)*tanh(g) = [c*di*dg + (eg-1)*df] / (df*di*dg)
//  sigm(o)*tanh(c')            = (ec-1) / ((1+eo)*(1+ec))
__device__ __forceinline__ unsigned act_unit(const f32x4 z, float& c) {
    const float L2E = 1.4426950408889634f;
    float ei = __builtin_amdgcn_exp2f(z[0] * -L2E);       // e^{-i}
    float ef = __builtin_amdgcn_exp2f(z[1] * -L2E);       // e^{-f}
    float eg = __builtin_amdgcn_exp2f(z[2] * (2.0f * L2E)); // e^{2g}
    float eo = __builtin_amdgcn_exp2f(z[3] * -L2E);       // e^{-o}
    float di = 1.0f + ei, df = 1.0f + ef, dg = 1.0f + eg;
    float m1 = di * dg;
    float num = c * m1 + (eg - 1.0f) * df;
    float r = __builtin_amdgcn_rcpf(df * m1);
    c = num * r;
    float ec = __builtin_amdgcn_exp2f(c * (2.0f * L2E));  // e^{2c'}
    float r2 = __builtin_amdgcn_rcpf((1.0f + eo) * (1.0f + ec));
    float h = (ec - 1.0f) * r2;
    return hpack(h);
}

__device__ __forceinline__ unsigned bperm(int idx, unsigned v) {
    return (unsigned)__builtin_amdgcn_ds_bpermute(idx, (int)v);
}
__device__ __forceinline__ bf16x8 bfrag(unsigned v0, unsigned v1) {
    uint4 u{v0, v0, v1, v1};
    return __builtin_bit_cast(bf16x8, u);
}
// MFMA with compressed A-fragment: expand (W0hi|W0lo, W1hi|W1lo) ->
// (W0hi,W0hi,W0lo,W0lo,W1hi,W1hi,W1lo,W1lo) via 4 v_perm. volatile asm fence
// blocks LICM from hoisting the expansion (which would re-inflate registers).
__device__ __forceinline__ f32x4 MFc(uint2 cf, bf16x8 b, f32x4 acc) {
    asm volatile("" : "+v"(cf.x), "+v"(cf.y));
    unsigned d0 = __builtin_amdgcn_perm(cf.x, cf.x, 0x01000100u);
    unsigned d1 = __builtin_amdgcn_perm(cf.x, cf.x, 0x03020302u);
    unsigned d2 = __builtin_amdgcn_perm(cf.y, cf.y, 0x01000100u);
    unsigned d3 = __builtin_amdgcn_perm(cf.y, cf.y, 0x03020302u);
    uint4 u{d0, d1, d2, d3};
    return __builtin_amdgcn_mfma_f32_16x16x32_bf16(
        __builtin_bit_cast(bf16x8, u), b, acc, 0, 0, 0);
}

// ---------- pre-kernel: build COMPRESSED A-fragments (15 x 64 lanes x 2 dw) ----------
__global__ void build_afrags(const float* Wk1, const float* Wr1, const float* b1,
                             const float* Wk2, const float* Wr2, const float* b2,
                             const float* Wk3, const float* Wr3, const float* b3,
                             const float* Wd,  const float* bd, unsigned* ws) {
    const int lane = threadIdx.x;  // 64 threads
    const int m = lane & 15;
    const int qh = lane >> 4;

    // ---- L1: ids 0..5 (tau*2+kap), U=10 ----
    for (int tau = 0; tau < 3; ++tau)
    for (int kap = 0; kap < 2; ++kap) {
        unsigned short h4[2][2];   // [input][hi/lo]
        for (int ii = 0; ii < 2; ++ii) {
            const int i = kap * 8 + qh * 2 + ii;
            const int u = tau * 4 + (m >> 2), col = (m & 3) * NU1 + u;
            unsigned short hi = 0, lo = 0;
            if (u < NU1 && i <= 15) {
                float W;
                if (i < 8)       W = Wr1[((i >> 1) + 4 * (i & 1)) * 40 + col];
                else if (i < 10) W = Wr1[i * 40 + col];
                else if (i < 15) W = Wk1[(i - 10) * 40 + col];
                else             W = b1[col];
                hi = bf16_hi_rne(W);
                lo = bf16_trunc(W - bf16_to_f(hi));
            }
            h4[ii][0] = hi; h4[ii][1] = lo;
        }
        const int id = tau * 2 + kap;
        ws[id * 128 + lane * 2 + 0] = (unsigned)h4[0][0] | ((unsigned)h4[0][1] << 16);
        ws[id * 128 + lane * 2 + 1] = (unsigned)h4[1][0] | ((unsigned)h4[1][1] << 16);
    }
    // ---- L2: ids 6..11 (6+tau*3+kap), U=7 ----
    for (int tau = 0; tau < 2; ++tau)
    for (int kap = 0; kap < 3; ++kap) {
        unsigned short h4[2][2];
        for (int ii = 0; ii < 2; ++ii) {
            const int i = kap * 8 + qh * 2 + ii;
            const int u = tau * 4 + (m >> 2), col = (m & 3) * NU2 + u;
            unsigned short hi = 0, lo = 0;
            if (u < NU2 && i <= 17) {
                float W;
                if (i < 8)        W = Wk2[((i >> 1) + 4 * (i & 1)) * 28 + col];
                else if (i < 10)  W = Wk2[i * 28 + col];
                else if (i < 16)  W = Wr2[(((i - 10) >> 1) + 4 * ((i - 10) & 1)) * 28 + col];
                else if (i == 16) W = Wr2[3 * 28 + col];
                else              W = b2[col];
                hi = bf16_hi_rne(W);
                lo = bf16_trunc(W - bf16_to_f(hi));
            }
            h4[ii][0] = hi; h4[ii][1] = lo;
        }
        const int id = 6 + tau * 3 + kap;
        ws[id * 128 + lane * 2 + 0] = (unsigned)h4[0][0] | ((unsigned)h4[0][1] << 16);
        ws[id * 128 + lane * 2 + 1] = (unsigned)h4[1][0] | ((unsigned)h4[1][1] << 16);
    }
    // ---- L3: ids 12,13, U=4 (single M-tile) ----
    for (int kap = 0; kap < 2; ++kap) {
        unsigned short h4[2][2];
        for (int ii = 0; ii < 2; ++ii) {
            const int i = kap * 8 + qh * 2 + ii;
            const int u = m >> 2, col = (m & 3) * NU3 + u;
            unsigned short hi = 0, lo = 0;
            if (i <= 11) {
                float W;
                if (i < 6)       W = Wk3[((i >> 1) + 4 * (i & 1)) * 16 + col];
                else if (i == 6) W = Wk3[3 * 16 + col];
                else if (i < 11) W = Wr3[(i - 7) * 16 + col];
                else             W = b3[col];
                hi = bf16_hi_rne(W);
                lo = bf16_trunc(W - bf16_to_f(hi));
            }
            h4[ii][0] = hi; h4[ii][1] = lo;
        }
        const int id = 12 + kap;
        ws[id * 128 + lane * 2 + 0] = (unsigned)h4[0][0] | ((unsigned)h4[0][1] << 16);
        ws[id * 128 + lane * 2 + 1] = (unsigned)h4[1][0] | ((unsigned)h4[1][1] << 16);
    }
    // ---- D: id 14, rows REPLICATED: row m -> output (m&3) ----
    {
        unsigned short h4[2][2];
        for (int ii = 0; ii < 2; ++ii) {
            const int i = qh * 2 + ii;
            unsigned short hi = 0, lo = 0;
            if (i <= 4) {
                float W = (i < 4) ? Wd[i * NOUT + (m & 3)] : bd[m & 3];
                hi = bf16_hi_rne(W);
                lo = bf16_trunc(W - bf16_to_f(hi));
            }
            h4[ii][0] = hi; h4[ii][1] = lo;
        }
        ws[14 * 128 + lane * 2 + 0] = (unsigned)h4[0][0] | ((unsigned)h4[0][1] << 16);
        ws[14 * 128 + lane * 2 + 1] = (unsigned)h4[1][0] | ((unsigned)h4[1][1] << 16);
    }
}

// ---------- main kernel: one group per wave, target 5 waves/SIMD ----------
__global__ __launch_bounds__(256, 5) void lstm3_mfma(
    const float* __restrict__ x, const unsigned* __restrict__ wsA,
    float* __restrict__ out, int B) {
    const int tid = threadIdx.x;
    const int lane = tid & 63;
    const int n = lane & 15;        // batch elem within group
    const int q = lane >> 4;        // K-quad / unit-quad

    // compressed A-fragments: 15 x 8B per lane
    uint2 cf[15];
#pragma unroll
    for (int i = 0; i < 15; ++i)
        cf[i] = ((const uint2*)wsA)[i * 64 + lane];

    // loop-invariant bpermute byte indices
    const int i_h19 = (n + 16) << 2;                    // read q'=1
    const int i_sh  = (n + 16 * ((q + 3) & 3)) << 2;    // read q'=q-1
    const int i_r1  = (n + 16 * ((q + 1) & 3)) << 2;    // read q'=q+1
    const int i_r2  = (n + 16 * ((q + 2) & 3)) << 2;    // read q'=q+2

    const f32x4 zro = {0.f, 0.f, 0.f, 0.f};

    const int ngrp = B >> 4;
    const int gw = (blockIdx.x * blockDim.x + tid) >> 6;
    const int nw = (gridDim.x * blockDim.x) >> 6;

    for (int grp = gw; grp < ngrp; grp += nw) {
        const float* xr = x + (size_t)grp * 16 * (SEQ * FEAT) + n * (SEQ * FEAT);
        float* ob = out + (size_t)grp * 16 * (SEQ * NOUT) + n * (SEQ * NOUT);

        unsigned p1a = 0, p1b = 0, p1c = 0, t9 = 0;
        unsigned p2a = 0, p2b = 0, p3 = 0, rot = 0, rot2 = 0;
        float c10 = 0.f, c11 = 0.f, c12 = 0.f, c20 = 0.f, c21 = 0.f, c30 = 0.f;
        float d0 = 0.f, d1 = 0.f, d2 = 0.f, d3 = 0.f;

        // preload x for t=0: q=1:(x0,x1) q=2:(x2,x3) q=3:(x4,-)
        float xa = 0.f, xc = 0.f;
        if (q != 0) {
            const float* p = xr + 2 * (q - 1);
            xa = p[0];
            if (q != 3) xc = p[1];
        }

#pragma unroll 1
        for (int t = 0; t < SEQ; ++t) {
            const unsigned xP0 = hpack(xa), xP1 = hpack(xc);
            // software prefetch next timestep's x
            {
                const int tn = (t + 1 < SEQ) ? t + 1 : 0;
                if (q != 0) {
                    const float* p = xr + tn * FEAT + 2 * (q - 1);
                    xa = p[0];
                    if (q != 3) xc = p[1];
                }
            }
            // ---- L1: B-frags from h1^{t-1} (lane-local) + x_t ----
            bf16x8 bF0 = bfrag(p1a, p1b);                         // (h1_q, h1_{4+q})^{t-1}
            unsigned F1v0 = (q == 0) ? p1c : xP0;                 // h1_8 | x_{2q-2}
            unsigned F1v1 = (q == 0) ? t9 : ((q == 3) ? ONE_P : xP1);
            bf16x8 bF1 = bfrag(F1v0, F1v1);
            f32x4 z0 = MFc(cf[0], bF0, zro); z0 = MFc(cf[1], bF1, z0);
            f32x4 z1 = MFc(cf[2], bF0, zro); z1 = MFc(cf[3], bF1, z1);
            f32x4 z2 = MFc(cf[4], bF0, zro); z2 = MFc(cf[5], bF1, z2);
            // shift h2^{t-1} while L1 computes (no dependency)
            const unsigned s2a = bperm(i_sh, p2a);
            const unsigned s2b = bperm(i_sh, p2b);
            p1a = act_unit(z0, c10);                              // h1_q^t
            p1b = act_unit(z1, c11);                              // h1_{4+q}^t
            p1c = act_unit(z2, c12);                              // h1_{8+q}^t (q<2)
            t9  = bperm(i_h19, p1c);                              // h1_9^t
            // ---- L2: h1^t lane-local + h2^{t-1} shifted ----
            bf16x8 bA  = bfrag(p1a, p1b);
            unsigned F2v0 = (q == 0) ? p1c : s2a;                 // h1_8 | h2_{q-1}
            unsigned F2v1 = (q == 0) ? t9  : s2b;                 // h1_9 | h2_{q+3}
            bf16x8 bF2 = bfrag(F2v0, F2v1);
            bf16x8 bF3 = bfrag(s2a, ONE_P);                       // q0: (h2_3, b2)
            f32x4 y0 = MFc(cf[6], bA, zro);
            y0 = MFc(cf[7], bF2, y0);
            y0 = MFc(cf[8], bF3, y0);
            f32x4 y1 = MFc(cf[9], bA, zro);
            y1 = MFc(cf[10], bF2, y1);
            y1 = MFc(cf[11], bF3, y1);
            p2a = act_unit(y0, c20);                              // h2_q^t
            p2b = act_unit(y1, c21);                              // h2_{4+q}^t (q<3)
            // ---- L3: h2^t lane-local + h3^{t-1} via rot/rot2 (prev iter) ----
            bf16x8 bF4 = bfrag(p2a, (q == 3) ? rot : p2b);        // q3: (h2_3, h3_0^{t-1})
            unsigned F5v0 = (q == 0) ? rot  : rot2;               // h3_1 | h3_3
            unsigned F5v1 = (q == 0) ? rot2 : ONE_P;              // h3_2 | b3
            bf16x8 bF5 = bfrag(F5v0, F5v1);
            f32x4 w0 = MFc(cf[12], bF4, zro);
            w0 = MFc(cf[13], bF5, w0);
            p3 = act_unit(w0, c30);                               // h3_q^t
            rot  = bperm(i_r1, p3);                               // h3_{q+1}^t
            rot2 = bperm(i_r2, p3);                               // h3_{q+2}^t
            // ---- D: replicated rows -> every lane computes outputs 0..3 ----
            unsigned F6v0 = (q == 0) ? p3 : ((q == 1) ? rot : ONE_P);
            unsigned F6v1 = (q == 0) ? rot : rot2;
            f32x4 o0 = MFc(cf[14], bfrag(F6v0, F6v1), zro);
            // keep output index q for this lane, defer sigmoid
            {
                float v01 = (q & 1) ? o0[1] : o0[0];
                float v23 = (q & 1) ? o0[3] : o0[2];
                float v = (q & 2) ? v23 : v01;
                const int r = t & 3;                              // uniform
                d0 = (r == 0) ? v : d0;
                d1 = (r == 1) ? v : d1;
                d2 = (r == 2) ? v : d2;
                d3 = (r == 3) ? v : d3;
            }
            if ((t & 3) == 3) {                                   // uniform branch
                float* p = ob + (t - 3) * NOUT + q;
                p[0 * NOUT] = sigm(d0);
                p[1 * NOUT] = sigm(d1);
                p[2 * NOUT] = sigm(d2);
                p[3 * NOUT] = sigm(d3);
            }
        }
    }
}

extern "C" void kernel_launch(void* const* d_in, const int* in_sizes, int n_in,
                              void* d_out, int out_size, void* d_ws, size_t ws_size,
                              hipStream_t stream) {
    const float* x   = (const float*)d_in[0];
    const float* Wk1 = (const float*)d_in[1];
    const float* Wr1 = (const float*)d_in[2];
    const float* b1  = (const float*)d_in[3];
    const float* Wk2 = (const float*)d_in[4];
    const float* Wr2 = (const float*)d_in[5];
    const float* b2  = (const float*)d_in[6];
    const float* Wk3 = (const float*)d_in[7];
    const float* Wr3 = (const float*)d_in[8];
    const float* b3  = (const float*)d_in[9];
    const float* Wd  = (const float*)d_in[10];
    const float* bd  = (const float*)d_in[11];
    float* out = (float*)d_out;
    unsigned* ws = (unsigned*)d_ws;

    const int B = in_sizes[0] / (SEQ * FEAT);

    build_afrags<<<1, 64, 0, stream>>>(Wk1, Wr1, b1, Wk2, Wr2, b2,
                                       Wk3, Wr3, b3, Wd, bd, ws);
    lstm3_mfma<<<4096, 256, 0, stream>>>(x, ws, out, B);
}

// Round 6
// 363.847 us; speedup vs baseline: 1.0446x; 1.0446x over previous
//
#include <hip/hip_runtime.h>

// ---- problem constants ----
static constexpr int SEQ = 20, FEAT = 5, NU1 = 10, NU2 = 7, NU3 = 4, NOUT = 4;

// MFMA fragment types
typedef short bf16x8 __attribute__((ext_vector_type(8)));
typedef float f32x4  __attribute__((ext_vector_type(4)));

static constexpr unsigned ONE_P = 0x3F803F80u;   // P(1.0): B K-slots (1,1,1,1)

// ---- K-slot scheme ----
// Input i -> 4 K-slots: A=(Whi,Whi,Wlo,Wlo), B=(vhi,vlo,vhi,vlo); sum=(Whi+Wlo)(vhi+vlo).
// Bias: A=(bhi,blo,0,0), B=P(1.0) -> bhi+blo exact.
// A-fragments (15 x 64 lanes x 16B, wave-uniform table) live in LDS, shared by
// all waves of the block; each MFMA does one ds_read_b128 (stride-16, conflict
// free). This keeps the loop-invariant pool OUT of registers -> 6 waves/SIMD.
// Lane (n = lane&15 batch-col, q = lane>>4) supplies B inputs (8*kap+2q, 8*kap+2q+1).
// INTERLEAVED input orderings make recurrent B-frags lane-local:
//  L1: [h1_0,h1_4,h1_1,h1_5,h1_2,h1_6,h1_3,h1_7 | h1_8,h1_9,x0..x4,b1]
//  L2: [h1 pairs | h1_8,h1_9,h2_0,h2_4,h2_1,h2_5 | h2_2,h2_6,h2_3,b2]
//  L3: [h2_0,h2_4,h2_1,h2_5,h2_2,h2_6,h2_3,h3_0 | h3_1,h3_2,h3_3,b3]
//  D : [h3_0,h3_1,h3_2,h3_3,bd], A-rows REPLICATED so every lane gets all 4 outputs.
// Cross-lane: 5 bpermutes/timestep (t9, s2a/s2b, rot/rot2).
// Dense sigmoid DEFERRED: 4 sigm/t -> 1 sigm/t amortized.
// Gate activations: combined reciprocals (5 exp + 2 rcp per act).

__device__ __forceinline__ unsigned short bf16_hi_rne(float x) {
    unsigned u = __float_as_uint(x);
    return (unsigned short)((u + 0x7FFF + ((u >> 16) & 1)) >> 16);
}
__device__ __forceinline__ unsigned short bf16_trunc(float x) {
    return (unsigned short)(__float_as_uint(x) >> 16);
}
__device__ __forceinline__ float bf16_to_f(unsigned short h) {
    return __uint_as_float(((unsigned)h) << 16);
}
// pack value as (hi | lo<<16): hi = RNE bf16 via v_cvt_pk, lo = trunc(h - hi)
__device__ __forceinline__ unsigned hpack(float h) {
    unsigned rp;
    asm("v_cvt_pk_bf16_f32 %0, %1, %1" : "=v"(rp) : "v"(h));
    float lo = h - __uint_as_float(rp << 16);
    return __builtin_amdgcn_perm(__float_as_uint(lo), rp, 0x07060100u);
}

__device__ __forceinline__ float sigm(float x) {
    return __builtin_amdgcn_rcpf(1.0f + __builtin_amdgcn_exp2f(x * -1.4426950408889634f));
}

// z = (i,f,g,o) for one unit (lane-local); updates c, returns packed h (hi,lo).
// Combined-reciprocal form: 5 exp + 2 rcp (validated in round 5).
__device__ __forceinline__ unsigned act_unit(const f32x4 z, float& c) {
    const float L2E = 1.4426950408889634f;
    float ei = __builtin_amdgcn_exp2f(z[0] * -L2E);         // e^{-i}
    float ef = __builtin_amdgcn_exp2f(z[1] * -L2E);         // e^{-f}
    float eg = __builtin_amdgcn_exp2f(z[2] * (2.0f * L2E)); // e^{2g}
    float eo = __builtin_amdgcn_exp2f(z[3] * -L2E);         // e^{-o}
    float di = 1.0f + ei, df = 1.0f + ef, dg = 1.0f + eg;
    float m1 = di * dg;
    float num = c * m1 + (eg - 1.0f) * df;
    float r = __builtin_amdgcn_rcpf(df * m1);
    c = num * r;
    float ec = __builtin_amdgcn_exp2f(c * (2.0f * L2E));    // e^{2c'}
    float r2 = __builtin_amdgcn_rcpf((1.0f + eo) * (1.0f + ec));
    float h = (ec - 1.0f) * r2;
    return hpack(h);
}

__device__ __forceinline__ unsigned bperm(int idx, unsigned v) {
    return (unsigned)__builtin_amdgcn_ds_bpermute(idx, (int)v);
}
__device__ __forceinline__ bf16x8 bfrag(unsigned v0, unsigned v1) {
    uint4 u{v0, v0, v1, v1};
    return __builtin_bit_cast(bf16x8, u);
}
__device__ __forceinline__ f32x4 MF(bf16x8 a, bf16x8 b, f32x4 c) {
    return __builtin_amdgcn_mfma_f32_16x16x32_bf16(a, b, c, 0, 0, 0);
}

// ---------- pre-kernel: build A-fragments into ws (15 frags x 64 lanes x 16B) ----------
__global__ void build_afrags(const float* Wk1, const float* Wr1, const float* b1,
                             const float* Wk2, const float* Wr2, const float* b2,
                             const float* Wk3, const float* Wr3, const float* b3,
                             const float* Wd,  const float* bd, unsigned* ws) {
    const int lane = threadIdx.x;  // 64 threads
    const int m = lane & 15;
    const int qh = lane >> 4;

    // ---- L1: ids 0..5 (tau*2+kap), U=10 ----
    for (int tau = 0; tau < 3; ++tau)
    for (int kap = 0; kap < 2; ++kap) {
        unsigned short h8[8];
        for (int j = 0; j < 8; ++j) {
            const int k = kap * 32 + qh * 8 + j;
            const int i = k >> 2, cls = k & 3;
            const int u = tau * 4 + (m >> 2), col = (m & 3) * NU1 + u;
            unsigned short v = 0;
            if (u < NU1) {
                if (i < 15) {
                    float W;
                    if (i < 8)       W = Wr1[((i >> 1) + 4 * (i & 1)) * 40 + col];
                    else if (i < 10) W = Wr1[i * 40 + col];
                    else             W = Wk1[(i - 10) * 40 + col];
                    unsigned short hi = bf16_hi_rne(W);
                    v = (cls < 2) ? hi : bf16_trunc(W - bf16_to_f(hi));
                } else if (i == 15) {
                    float bv = b1[col];
                    unsigned short hi = bf16_hi_rne(bv);
                    v = (cls == 0) ? hi : ((cls == 1) ? bf16_trunc(bv - bf16_to_f(hi)) : (unsigned short)0);
                }
            }
            h8[j] = v;
        }
        const int id = tau * 2 + kap;
        for (int d = 0; d < 4; ++d)
            ws[id * 256 + lane * 4 + d] = (unsigned)h8[2 * d] | ((unsigned)h8[2 * d + 1] << 16);
    }
    // ---- L2: ids 6..11 (6+tau*3+kap), U=7 ----
    for (int tau = 0; tau < 2; ++tau)
    for (int kap = 0; kap < 3; ++kap) {
        unsigned short h8[8];
        for (int j = 0; j < 8; ++j) {
            const int k = kap * 32 + qh * 8 + j;
            const int i = k >> 2, cls = k & 3;
            const int u = tau * 4 + (m >> 2), col = (m & 3) * NU2 + u;
            unsigned short v = 0;
            if (u < NU2) {
                if (i < 17) {
                    float W;
                    if (i < 8)        W = Wk2[((i >> 1) + 4 * (i & 1)) * 28 + col];
                    else if (i < 10)  W = Wk2[i * 28 + col];
                    else if (i < 16)  W = Wr2[(((i - 10) >> 1) + 4 * ((i - 10) & 1)) * 28 + col];
                    else              W = Wr2[3 * 28 + col];
                    unsigned short hi = bf16_hi_rne(W);
                    v = (cls < 2) ? hi : bf16_trunc(W - bf16_to_f(hi));
                } else if (i == 17) {
                    float bv = b2[col];
                    unsigned short hi = bf16_hi_rne(bv);
                    v = (cls == 0) ? hi : ((cls == 1) ? bf16_trunc(bv - bf16_to_f(hi)) : (unsigned short)0);
                }
            }
            h8[j] = v;
        }
        const int id = 6 + tau * 3 + kap;
        for (int d = 0; d < 4; ++d)
            ws[id * 256 + lane * 4 + d] = (unsigned)h8[2 * d] | ((unsigned)h8[2 * d + 1] << 16);
    }
    // ---- L3: ids 12,13, U=4 (single M-tile) ----
    for (int kap = 0; kap < 2; ++kap) {
        unsigned short h8[8];
        for (int j = 0; j < 8; ++j) {
            const int k = kap * 32 + qh * 8 + j;
            const int i = k >> 2, cls = k & 3;
            const int u = m >> 2, col = (m & 3) * NU3 + u;
            unsigned short v = 0;
            if (i < 11) {
                float W;
                if (i < 6)       W = Wk3[((i >> 1) + 4 * (i & 1)) * 16 + col];
                else if (i == 6) W = Wk3[3 * 16 + col];
                else             W = Wr3[(i - 7) * 16 + col];
                unsigned short hi = bf16_hi_rne(W);
                v = (cls < 2) ? hi : bf16_trunc(W - bf16_to_f(hi));
            } else if (i == 11) {
                float bv = b3[col];
                unsigned short hi = bf16_hi_rne(bv);
                v = (cls == 0) ? hi : ((cls == 1) ? bf16_trunc(bv - bf16_to_f(hi)) : (unsigned short)0);
            }
            h8[j] = v;
        }
        const int id = 12 + kap;
        for (int d = 0; d < 4; ++d)
            ws[id * 256 + lane * 4 + d] = (unsigned)h8[2 * d] | ((unsigned)h8[2 * d + 1] << 16);
    }
    // ---- D: id 14, rows REPLICATED: row m -> output (m&3), all row-quads ----
    {
        unsigned short h8[8];
        for (int j = 0; j < 8; ++j) {
            const int k = qh * 8 + j;
            const int i = k >> 2, cls = k & 3;
            unsigned short v = 0;
            if (i < 4) {
                float W = Wd[i * NOUT + (m & 3)];
                unsigned short hi = bf16_hi_rne(W);
                v = (cls < 2) ? hi : bf16_trunc(W - bf16_to_f(hi));
            } else if (i == 4) {
                float bv = bd[m & 3];
                unsigned short hi = bf16_hi_rne(bv);
                v = (cls == 0) ? hi : ((cls == 1) ? bf16_trunc(bv - bf16_to_f(hi)) : (unsigned short)0);
            }
            h8[j] = v;
        }
        for (int d = 0; d < 4; ++d)
            ws[14 * 256 + lane * 4 + d] = (unsigned)h8[2 * d] | ((unsigned)h8[2 * d + 1] << 16);
    }
}

// ---------- main kernel: A-frags in LDS (block-shared), 6 waves/SIMD ----------
__global__ __launch_bounds__(256, 6) void lstm3_mfma(
    const float* __restrict__ x, const unsigned* __restrict__ wsA,
    float* __restrict__ out, int B) {
    __shared__ __attribute__((aligned(16))) unsigned ldsA[15 * 256];  // 15360 B

    const int tid = threadIdx.x;
    const int lane = tid & 63;
    const int n = lane & 15;        // batch elem within group
    const int q = lane >> 4;        // K-quad / unit-quad

    // cooperative fill of the wave-uniform fragment table (once per block)
#pragma unroll
    for (int i = 0; i < 15; ++i)
        ldsA[i * 256 + tid] = wsA[i * 256 + tid];
    __syncthreads();

    // loop-invariant bpermute byte indices
    const int i_h19 = (n + 16) << 2;                    // read q'=1
    const int i_sh  = (n + 16 * ((q + 3) & 3)) << 2;    // read q'=q-1
    const int i_r1  = (n + 16 * ((q + 1) & 3)) << 2;    // read q'=q+1
    const int i_r2  = (n + 16 * ((q + 2) & 3)) << 2;    // read q'=q+2

    const f32x4 zro = {0.f, 0.f, 0.f, 0.f};

    const int ngrp = B >> 4;
    const int gw = (blockIdx.x * blockDim.x + tid) >> 6;
    const int nw = (gridDim.x * blockDim.x) >> 6;

    // opaque zero: makes frag addresses loop-variant so the 15 ds_reads can't
    // be hoisted into 60 live registers (keeps occupancy at 6 waves/SIMD)
    unsigned off = 0;

    for (int grp = gw; grp < ngrp; grp += nw) {
        const float* xr = x + (size_t)grp * 16 * (SEQ * FEAT) + n * (SEQ * FEAT);
        float* ob = out + (size_t)grp * 16 * (SEQ * NOUT) + n * (SEQ * NOUT);

        unsigned p1a = 0, p1b = 0, p1c = 0, t9 = 0;
        unsigned p2a = 0, p2b = 0, p3 = 0, rot = 0, rot2 = 0;
        float c10 = 0.f, c11 = 0.f, c12 = 0.f, c20 = 0.f, c21 = 0.f, c30 = 0.f;
        float d0 = 0.f, d1 = 0.f, d2 = 0.f, d3 = 0.f;

        // preload x for t=0: q=1:(x0,x1) q=2:(x2,x3) q=3:(x4,-)
        float xa = 0.f, xc = 0.f;
        if (q != 0) {
            const float* p = xr + 2 * (q - 1);
            xa = p[0];
            if (q != 3) xc = p[1];
        }

#pragma unroll 1
        for (int t = 0; t < SEQ; ++t) {
            asm volatile("" : "+v"(off));
            const unsigned* Sf = ldsA + lane * 4 + off;
#define LDF(id) (*(const bf16x8*)(Sf + (id) * 256))

            const unsigned xP0 = hpack(xa), xP1 = hpack(xc);
            // software prefetch next timestep's x
            {
                const int tn = (t + 1 < SEQ) ? t + 1 : 0;
                if (q != 0) {
                    const float* p = xr + tn * FEAT + 2 * (q - 1);
                    xa = p[0];
                    if (q != 3) xc = p[1];
                }
            }
            // ---- L1: B-frags from h1^{t-1} (lane-local) + x_t ----
            bf16x8 bF0 = bfrag(p1a, p1b);                         // (h1_q, h1_{4+q})^{t-1}
            unsigned F1v0 = (q == 0) ? p1c : xP0;                 // h1_8 | x_{2q-2}
            unsigned F1v1 = (q == 0) ? t9 : ((q == 3) ? ONE_P : xP1);
            bf16x8 bF1 = bfrag(F1v0, F1v1);
            f32x4 z0 = MF(LDF(0), bF0, zro); z0 = MF(LDF(1), bF1, z0);
            f32x4 z1 = MF(LDF(2), bF0, zro); z1 = MF(LDF(3), bF1, z1);
            f32x4 z2 = MF(LDF(4), bF0, zro); z2 = MF(LDF(5), bF1, z2);
            // shift h2^{t-1} while L1 computes (no dependency)
            const unsigned s2a = bperm(i_sh, p2a);
            const unsigned s2b = bperm(i_sh, p2b);
            p1a = act_unit(z0, c10);                              // h1_q^t
            p1b = act_unit(z1, c11);                              // h1_{4+q}^t
            p1c = act_unit(z2, c12);                              // h1_{8+q}^t (q<2)
            t9  = bperm(i_h19, p1c);                              // h1_9^t
            // ---- L2: h1^t lane-local + h2^{t-1} shifted ----
            bf16x8 bA  = bfrag(p1a, p1b);
            unsigned F2v0 = (q == 0) ? p1c : s2a;                 // h1_8 | h2_{q-1}
            unsigned F2v1 = (q == 0) ? t9  : s2b;                 // h1_9 | h2_{q+3}
            bf16x8 bF2 = bfrag(F2v0, F2v1);
            bf16x8 bF3 = bfrag(s2a, ONE_P);                       // q0: (h2_3, b2)
            f32x4 y0 = MF(LDF(6), bA, zro);
            y0 = MF(LDF(7), bF2, y0);
            y0 = MF(LDF(8), bF3, y0);
            f32x4 y1 = MF(LDF(9), bA, zro);
            y1 = MF(LDF(10), bF2, y1);
            y1 = MF(LDF(11), bF3, y1);
            p2a = act_unit(y0, c20);                              // h2_q^t
            p2b = act_unit(y1, c21);                              // h2_{4+q}^t (q<3)
            // ---- L3: h2^t lane-local + h3^{t-1} via rot/rot2 (prev iter) ----
            bf16x8 bF4 = bfrag(p2a, (q == 3) ? rot : p2b);        // q3: (h2_3, h3_0^{t-1})
            unsigned F5v0 = (q == 0) ? rot  : rot2;               // h3_1 | h3_3
            unsigned F5v1 = (q == 0) ? rot2 : ONE_P;              // h3_2 | b3
            bf16x8 bF5 = bfrag(F5v0, F5v1);
            f32x4 w0 = MF(LDF(12), bF4, zro);
            w0 = MF(LDF(13), bF5, w0);
            p3 = act_unit(w0, c30);                               // h3_q^t
            rot  = bperm(i_r1, p3);                               // h3_{q+1}^t
            rot2 = bperm(i_r2, p3);                               // h3_{q+2}^t
            // ---- D: replicated rows -> every lane computes outputs 0..3 ----
            unsigned F6v0 = (q == 0) ? p3 : ((q == 1) ? rot : ONE_P);
            unsigned F6v1 = (q == 0) ? rot : rot2;
            f32x4 o0 = MF(LDF(14), bfrag(F6v0, F6v1), zro);
            // keep output index q for this lane, defer sigmoid
            {
                float v01 = (q & 1) ? o0[1] : o0[0];
                float v23 = (q & 1) ? o0[3] : o0[2];
                float v = (q & 2) ? v23 : v01;
                const int r = t & 3;                              // uniform
                d0 = (r == 0) ? v : d0;
                d1 = (r == 1) ? v : d1;
                d2 = (r == 2) ? v : d2;
                d3 = (r == 3) ? v : d3;
            }
            if ((t & 3) == 3) {                                   // uniform branch
                float* p = ob + (t - 3) * NOUT + q;
                p[0 * NOUT] = sigm(d0);
                p[1 * NOUT] = sigm(d1);
                p[2 * NOUT] = sigm(d2);
                p[3 * NOUT] = sigm(d3);
            }
#undef LDF
        }
    }
}

extern "C" void kernel_launch(void* const* d_in, const int* in_sizes, int n_in,
                              void* d_out, int out_size, void* d_ws, size_t ws_size,
                              hipStream_t stream) {
    const float* x   = (const float*)d_in[0];
    const float* Wk1 = (const float*)d_in[1];
    const float* Wr1 = (const float*)d_in[2];
    const float* b1  = (const float*)d_in[3];
    const float* Wk2 = (const float*)d_in[4];
    const float* Wr2 = (const float*)d_in[5];
    const float* b2  = (const float*)d_in[6];
    const float* Wk3 = (const float*)d_in[7];
    const float* Wr3 = (const float*)d_in[8];
    const float* b3  = (const float*)d_in[9];
    const float* Wd  = (const float*)d_in[10];
    const float* bd  = (const float*)d_in[11];
    float* out = (float*)d_out;
    unsigned* ws = (unsigned*)d_ws;

    const int B = in_sizes[0] / (SEQ * FEAT);

    build_afrags<<<1, 64, 0, stream>>>(Wk1, Wr1, b1, Wk2, Wr2, b2,
                                       Wk3, Wr3, b3, Wd, bd, ws);
    lstm3_mfma<<<4096, 256, 0, stream>>>(x, ws, out, B);
}